// Round 3
// baseline (304.769 us; speedup 1.0000x reference)
//
#include <hip/hip_runtime.h>
#include <stdint.h>

#define NB 8
#define NP 100
#define NT 500
#define NV 128
#define NBP 800   // NB*NP
#define TILE 8
#define DPB 512   // k_dp block size (8 waves -> 2 waves/SIMD)

// ---------------- Threefry-2x32, key = (0,1) (jax.random.key(1)) ----------------
__device__ __forceinline__ void threefry01(uint32_t x0, uint32_t x1,
                                           uint32_t& o0, uint32_t& o1) {
  const uint32_t k0 = 0u, k1 = 1u;
  const uint32_t k2 = 0x1BD11BDAu ^ k0 ^ k1;  // 0x1BD11BDB
  x0 += k0; x1 += k1;
#define TF_R(r) { x0 += x1; x1 = __builtin_rotateleft32(x1, (r)); x1 ^= x0; }
  TF_R(13) TF_R(15) TF_R(26) TF_R(6)
  x0 += k1; x1 += k2 + 1u;
  TF_R(17) TF_R(29) TF_R(16) TF_R(24)
  x0 += k2; x1 += k0 + 2u;
  TF_R(13) TF_R(15) TF_R(26) TF_R(6)
  x0 += k0; x1 += k1 + 3u;
  TF_R(17) TF_R(29) TF_R(16) TF_R(24)
  x0 += k1; x1 += k2 + 4u;
  TF_R(13) TF_R(15) TF_R(26) TF_R(6)
  x0 += k2; x1 += k0 + 5u;
#undef TF_R
  o0 = x0; o1 = x1;
}

// bits -> uniform(1e-6, 1-1e-6) exactly as jax._src.random._uniform (f32)
// (expression kept byte-identical to the round that passed — do not perturb)
__device__ __forceinline__ float bits_to_u(uint32_t bits) {
  const float minv = 1e-6f;
  const float maxv = (float)(1.0 - 1e-6);
  const float span = maxv - minv;
  float f = __uint_as_float((bits >> 9) | 0x3f800000u) - 1.0f;
  return fmaxf(minv, f * span + minv);
}

__device__ __forceinline__ float gumbel_from_bits(uint32_t bits) {
  float u = bits_to_u(bits);
  return -__logf(-__logf(u));   // precision only affects argmax near-ties
}

// ---------------- Kernel 1: Gumbel sampling + argmax over V=128 ----------------
// grid (NB, NT), block 256 (4 waves); wave w handles p = w, w+4, ... (25 each)
// writes tl[t*NBP+bp] = {token, bits(emissions[token])}
__global__ __launch_bounds__(256) void k_sample(
    const float* __restrict__ em, const int* __restrict__ elen,
    int2* __restrict__ tl) {
  const int b = blockIdx.x;
  const int t = blockIdx.y;
  if (t >= elen[b]) return;  // frames beyond length are never consumed
  __shared__ float e[NV];
  const int tid = threadIdx.x;
  if (tid < NV) e[tid] = em[(b * NT + t) * NV + tid];
  __syncthreads();
  const int wave = tid >> 6, lane = tid & 63;
  const float e_lo = e[lane], e_hi = e[lane + 64];
  const int outbase = t * NBP + b * NP;
  uint32_t base = (uint32_t)(((b * NP + wave) * NT + t) * NV) + (uint32_t)lane;
  for (int p = wave; p < NP; p += 4, base += 4u * NT * NV) {
    // partitionable threefry: bits[i] = low output of threefry(key, i>>32, i)
    uint32_t d0, ra, d1, rb;
    threefry01(0u, base, d0, ra);
    threefry01(0u, base + 64u, d1, rb);
    const float v0 = fmaf(e_lo, 0.5f, gumbel_from_bits(ra));
    const float v1 = fmaf(e_hi, 0.5f, gumbel_from_bits(rb));
    float mx = fmaxf(v0, v1);
    for (int off = 1; off < 64; off <<= 1) mx = fmaxf(mx, __shfl_xor(mx, off));
    // first-index tiebreak: any lo index beats any hi index (matches jnp.argmax)
    int bi;
    const unsigned long long mlo = __ballot(v0 == mx);
    if (mlo) bi = (int)__builtin_ctzll(mlo);
    else     bi = (int)__builtin_ctzll(__ballot(v1 == mx)) + 64;
    if (lane == 0) {
      tl[outbase + p] = make_int2(bi, __float_as_int(e[bi]));
    }
  }
}

// ---------------- Kernel 2: CTC collapse + Myers bit-parallel edit distance ----
// one lane per path; 2 blocks x 512 (2 waves/SIMD for latency interleave).
// T tiled by 8 with static-named double buffers (all reg indices compile-time).
struct DpState {
  unsigned long long Pv0, Pv1, Mv0, Mv1;
  int score, prev;
  double logp;
};

__device__ __forceinline__ void load_tile(int2 (&buf)[TILE], int tile,
                                          const int2* __restrict__ tl, int bpc) {
#pragma unroll
  for (int i = 0; i < TILE; i++) {
    int t = tile * TILE + i;
    t = t < NT ? t : NT - 1;
    buf[i] = tl[t * NBP + bpc];
  }
}

__device__ __forceinline__ void process_tile(
    const int2 (&buf)[TILE], int tile, int myel,
    const unsigned long long (*peqb)[2], int hw, unsigned long long hmask,
    DpState& st) {
  unsigned long long eq0[TILE], eq1[TILE];
#pragma unroll
  for (int i = 0; i < TILE; i++) {
    const int c = buf[i].x & 127;
    eq0[i] = peqb[c][0];
    eq1[i] = peqb[c][1];
  }
#pragma unroll
  for (int i = 0; i < TILE; i++) {
    const int t = tile * TILE + i;
    const bool valid = (t < myel);
    const int c = buf[i].x;
    const bool kept = valid && (c != 0) && (c != st.prev);
    if (valid) { st.logp += (double)__int_as_float(buf[i].y); st.prev = c; }
    if (kept) {
      const unsigned long long Eq0 = eq0[i], Eq1 = eq1[i];
      const unsigned long long Xv0 = Eq0 | st.Mv0, Xv1 = Eq1 | st.Mv1;
      const unsigned long long EP0 = Eq0 & st.Pv0, EP1 = Eq1 & st.Pv1;
      const unsigned long long sA = EP0 + st.Pv0;
      const unsigned long long sB = EP1 + st.Pv1 + (sA < EP0 ? 1ull : 0ull);
      const unsigned long long Xh0 = (sA ^ st.Pv0) | Eq0;
      const unsigned long long Xh1 = (sB ^ st.Pv1) | Eq1;
      const unsigned long long Ph0 = st.Mv0 | ~(Xh0 | st.Pv0);
      const unsigned long long Ph1 = st.Mv1 | ~(Xh1 | st.Pv1);
      const unsigned long long Mh0 = st.Pv0 & Xh0, Mh1 = st.Pv1 & Xh1;
      st.score += (int)(((hw ? Ph1 : Ph0) & hmask) != 0);
      st.score -= (int)(((hw ? Mh1 : Mh0) & hmask) != 0);
      const unsigned long long nPh1 = (Ph1 << 1) | (Ph0 >> 63);
      const unsigned long long nPh0 = (Ph0 << 1) | 1ull;   // dp[i][0] = i boundary
      const unsigned long long nMh1 = (Mh1 << 1) | (Mh0 >> 63);
      const unsigned long long nMh0 = (Mh0 << 1);
      st.Pv0 = nMh0 | ~(Xv0 | nPh0);
      st.Pv1 = nMh1 | ~(Xv1 | nPh1);
      st.Mv0 = nPh0 & Xv0;
      st.Mv1 = nPh1 & Xv1;
    }
  }
}

__global__ __launch_bounds__(DPB) void k_dp(
    const int2* __restrict__ tl,
    const int* __restrict__ elen, const int* __restrict__ labels,
    const int* __restrict__ llen,
    float* __restrict__ wer, float* __restrict__ logp_out) {
  __shared__ unsigned long long peq[NB][NV][2];  // 16 KB
  const int tid = threadIdx.x;
  const int bp = blockIdx.x * DPB + tid;
  for (int i = tid; i < NB * NV * 2; i += DPB) ((unsigned long long*)peq)[i] = 0ull;
  __syncthreads();
  // parallel build: one (b, i) label slot per thread, atomicOr into 32-bit halves
  for (int idx = tid; idx < NB * 100; idx += DPB) {
    const int bb = idx / 100, i = idx - bb * 100;
    if (i < llen[bb]) {
      const int c = labels[idx] & 127;
      atomicOr(((unsigned int*)&peq[bb][c][0]) + (i >> 5), 1u << (i & 31));
    }
  }
  __syncthreads();
  const bool active = (bp < NBP);
  const int bpc = active ? bp : (NBP - 1);
  const int b = bpc / NP;
  const int myel = elen[b];
  const int m = llen[b];  // ref_len in [80,100]
  int tmax = myel;
  for (int off = 1; off < 64; off <<= 1) {
    int o = __shfl_xor(tmax, off);
    tmax = o > tmax ? o : tmax;
  }
  const int ntiles = (tmax + TILE - 1) / TILE;  // >= 50 always

  DpState st;
  st.Pv0 = ~0ull; st.Pv1 = ~0ull; st.Mv0 = 0ull; st.Mv1 = 0ull;
  st.score = m; st.prev = -1; st.logp = 0.0;
  const int hw = (m - 1) >> 6;
  const unsigned long long hmask = 1ull << ((m - 1) & 63);
  const unsigned long long (*peqb)[2] = peq[b];

  int2 bufA[TILE], bufB[TILE];
  load_tile(bufA, 0, tl, bpc);
  load_tile(bufB, 1, tl, bpc);
  for (int tile = 0; tile < ntiles; tile += 2) {
    process_tile(bufA, tile, myel, peqb, hw, hmask, st);
    if (tile + 2 < ntiles) load_tile(bufA, tile + 2, tl, bpc);
    if (tile + 1 < ntiles) {
      process_tile(bufB, tile + 1, myel, peqb, hw, hmask, st);
      if (tile + 3 < ntiles) load_tile(bufB, tile + 3, tl, bpc);
    }
  }
  if (active) { wer[bp] = (float)st.score; logp_out[bp] = (float)st.logp; }
}

// ---------------- Kernel 3: per-b softmax over P, expected WER, mean -----------
__global__ __launch_bounds__(512) void k_final(
    const float* __restrict__ wer, const float* __restrict__ logp,
    float* __restrict__ out) {
  __shared__ float partial[NB];
  const int w = threadIdx.x >> 6, lane = threadIdx.x & 63;
  const int base = w * NP;
  float l0 = (lane < NP) ? logp[base + lane] : -1e30f;
  float l1 = (lane + 64 < NP) ? logp[base + lane + 64] : -1e30f;
  float mx = fmaxf(l0, l1);
  for (int off = 1; off < 64; off <<= 1) mx = fmaxf(mx, __shfl_xor(mx, off));
  const float e0 = (lane < NP) ? __expf(l0 - mx) : 0.0f;
  const float e1 = (lane + 64 < NP) ? __expf(l1 - mx) : 0.0f;
  const float w0 = (lane < NP) ? wer[base + lane] : 0.0f;
  const float w1 = (lane + 64 < NP) ? wer[base + lane + 64] : 0.0f;
  float s = e0 + e1;
  float a = e0 * w0 + e1 * w1;
  for (int off = 1; off < 64; off <<= 1) {
    s += __shfl_xor(s, off);
    a += __shfl_xor(a, off);
  }
  if (lane == 0) partial[w] = a / s;
  __syncthreads();
  if (threadIdx.x == 0) {
    float tot = 0.0f;
    for (int i = 0; i < NB; i++) tot += partial[i];
    out[0] = tot * (1.0f / (float)NBP);
  }
}

extern "C" void kernel_launch(void* const* d_in, const int* in_sizes, int n_in,
                              void* d_out, int out_size, void* d_ws, size_t ws_size,
                              hipStream_t stream) {
  const float* em     = (const float*)d_in[0];
  const int*   elen   = (const int*)d_in[1];
  const int*   labels = (const int*)d_in[2];
  const int*   llen   = (const int*)d_in[3];
  float* out = (float*)d_out;
  char* ws = (char*)d_ws;
  int2*  tlb  = (int2*)ws;                                  // 500*800*8 = 3.2 MB
  float* wer  = (float*)(ws + (size_t)NT * NBP * 8);        // 3.2 KB
  float* logp = (float*)(ws + (size_t)NT * NBP * 8 + NBP * 4);

  k_sample<<<dim3(NB, NT), dim3(256), 0, stream>>>(em, elen, tlb);
  k_dp<<<dim3(2), dim3(DPB), 0, stream>>>(tlb, elen, labels, llen, wer, logp);
  k_final<<<dim3(1), dim3(512), 0, stream>>>(wer, logp, out);
}

// Round 4
// 237.043 us; speedup vs baseline: 1.2857x; 1.2857x over previous
//
#include <hip/hip_runtime.h>
#include <stdint.h>

#define NB 8
#define NP 100
#define NT 500
#define NV 128
#define NBP 800   // NB*NP
#define TILE 8

typedef unsigned long long u64;

// ---------------- Threefry-2x32, key = (0,1) (jax.random.key(1)) ----------------
__device__ __forceinline__ void threefry01(uint32_t x0, uint32_t x1,
                                           uint32_t& o0, uint32_t& o1) {
  const uint32_t k0 = 0u, k1 = 1u;
  const uint32_t k2 = 0x1BD11BDAu ^ k0 ^ k1;  // 0x1BD11BDB
  x0 += k0; x1 += k1;
#define TF_R(r) { x0 += x1; x1 = __builtin_rotateleft32(x1, (r)); x1 ^= x0; }
  TF_R(13) TF_R(15) TF_R(26) TF_R(6)
  x0 += k1; x1 += k2 + 1u;
  TF_R(17) TF_R(29) TF_R(16) TF_R(24)
  x0 += k2; x1 += k0 + 2u;
  TF_R(13) TF_R(15) TF_R(26) TF_R(6)
  x0 += k0; x1 += k1 + 3u;
  TF_R(17) TF_R(29) TF_R(16) TF_R(24)
  x0 += k1; x1 += k2 + 4u;
  TF_R(13) TF_R(15) TF_R(26) TF_R(6)
  x0 += k2; x1 += k0 + 5u;
#undef TF_R
  o0 = x0; o1 = x1;
}

// bits -> uniform(1e-6,1-1e-6) -> gumbel.  -ln(-ln u) computed as
// log2-based chain; bitwise-equal to __logf(-__logf(u)) lowering.
__device__ __forceinline__ float gumbel_from_bits(uint32_t bits) {
  const float minv = 1e-6f;
  const float span = (float)(1.0 - 1e-6) - 1e-6f;
  float f = __uint_as_float((bits >> 9) | 0x3f800000u) - 1.0f;
  float u = fmaxf(minv, fmaf(f, span, minv));
  float l2 = __log2f(u);                    // log2(u) < 0
  float nl = l2 * -0.69314718056f;          // -ln(u) > 0
  return __log2f(nl) * -0.69314718056f;     // -ln(-ln(u))
}

// ---------------- Kernel 1: Gumbel sampling + serial argmax over V=128 ---------
// grid (NB, NT), block 128: one LANE per path p = tid. The whole wave shares
// (b,t) -> e_row reads are wave-uniform (s_load), zero cross-lane ops.
// writes tl[t*NBP+bp] = {token, bits(emissions[token])}  (lane-coalesced)
__global__ __launch_bounds__(128) void k_sample(
    const float* __restrict__ em, const int* __restrict__ elen,
    int2* __restrict__ tl) {
  const int b = blockIdx.x;
  const int t = blockIdx.y;
  if (t >= elen[b]) return;  // frames beyond length are never consumed
  const int p = threadIdx.x;            // 0..127; active p < NP
  const float* __restrict__ e_row = em + (size_t)(b * NT + t) * NV;
  const uint32_t base =
      (uint32_t)(((b * NP + (p < NP ? p : 0)) * NT + t)) << 7;  // *NV
  float bv = -3.0e38f, be = 0.0f;
  int bi = 0;
#pragma unroll 16
  for (int v = 0; v < NV; v++) {
    // partitionable threefry: bits[i] = low output of threefry(key, i>>32, i)
    uint32_t d0, r;
    threefry01(0u, base + (uint32_t)v, d0, r);
    const float ev = e_row[v];
    const float val = fmaf(ev, 0.5f, gumbel_from_bits(r));
    if (val > bv) { bv = val; bi = v; be = ev; }  // strict > = first-index tiebreak
  }
  if (p < NP) tl[t * NBP + b * NP + p] = make_int2(bi, __float_as_int(be));
}

// ---------------- Kernel 2: CTC collapse + Myers bit-parallel edit distance ----
// one block per b (8 x 128), one lane per path p = tid (active p < 100).
// peq stored as 4 u32 planes pq[k][c] -> bank = c%32 -> <=2-way (free).
// Uniform elen/llen per block; static double-buffered distance-2 prefetch.
struct DpState {
  u64 Pv0, Pv1, Mv0, Mv1;
  int score, prev;
  double logp;
};

__device__ __forceinline__ void load_tile(int2 (&buf)[TILE], int tile,
                                          const int2* __restrict__ tl, int bpc) {
#pragma unroll
  for (int i = 0; i < TILE; i++) {
    int t = tile * TILE + i;
    t = t < NT ? t : NT - 1;
    buf[i] = tl[t * NBP + bpc];
  }
}

__device__ __forceinline__ void process_tile(
    const int2 (&buf)[TILE], int tile, int myel,
    const uint32_t (*pq)[NV], int hw, u64 hmask, DpState& st) {
  u64 eq0[TILE], eq1[TILE];
#pragma unroll
  for (int i = 0; i < TILE; i++) {
    const int c = buf[i].x & 127;
    eq0[i] = (u64)pq[0][c] | ((u64)pq[1][c] << 32);
    eq1[i] = (u64)pq[2][c] | ((u64)pq[3][c] << 32);
  }
#pragma unroll
  for (int i = 0; i < TILE; i++) {
    const int t = tile * TILE + i;
    if (t >= myel) break;  // uniform per block
    const int c = buf[i].x;
    const bool kept = (c != 0) && (c != st.prev);
    st.logp += (double)__int_as_float(buf[i].y);
    st.prev = c;
    if (kept) {
      const u64 Eq0 = eq0[i], Eq1 = eq1[i];
      const u64 Xv0 = Eq0 | st.Mv0, Xv1 = Eq1 | st.Mv1;
      const u64 EP0 = Eq0 & st.Pv0, EP1 = Eq1 & st.Pv1;
      const u64 sA = EP0 + st.Pv0;
      const u64 sB = EP1 + st.Pv1 + (sA < EP0 ? 1ull : 0ull);
      const u64 Xh0 = (sA ^ st.Pv0) | Eq0;
      const u64 Xh1 = (sB ^ st.Pv1) | Eq1;
      const u64 Ph0 = st.Mv0 | ~(Xh0 | st.Pv0);
      const u64 Ph1 = st.Mv1 | ~(Xh1 | st.Pv1);
      const u64 Mh0 = st.Pv0 & Xh0, Mh1 = st.Pv1 & Xh1;
      st.score += (int)(((hw ? Ph1 : Ph0) & hmask) != 0);
      st.score -= (int)(((hw ? Mh1 : Mh0) & hmask) != 0);
      const u64 nPh1 = (Ph1 << 1) | (Ph0 >> 63);
      const u64 nPh0 = (Ph0 << 1) | 1ull;   // dp[i][0] = i boundary
      const u64 nMh1 = (Mh1 << 1) | (Mh0 >> 63);
      const u64 nMh0 = (Mh0 << 1);
      st.Pv0 = nMh0 | ~(Xv0 | nPh0);
      st.Pv1 = nMh1 | ~(Xv1 | nPh1);
      st.Mv0 = nPh0 & Xv0;
      st.Mv1 = nPh1 & Xv1;
    }
  }
}

__global__ __launch_bounds__(128) void k_dp(
    const int2* __restrict__ tl,
    const int* __restrict__ elen, const int* __restrict__ labels,
    const int* __restrict__ llen,
    float* __restrict__ wer, float* __restrict__ logp_out) {
  __shared__ uint32_t pq[4][NV];  // [word-half][token], 2 KB, bank = c%32
  const int b = blockIdx.x;
  const int tid = threadIdx.x;
  const int m = llen[b];  // ref_len in [80,100], uniform
  {
    // build: thread c owns column c, branchless chunked bit-set
    const int c = tid;
    const int* __restrict__ lab = labels + b * 100;  // L == 100
    uint32_t a0 = 0, a1 = 0, a2 = 0, a3 = 0;
    const int e0 = m < 32 ? m : 32, e1 = m < 64 ? m : 64;
    const int e2 = m < 96 ? m : 96, e3 = m;
    for (int i = 0; i < e0; i++)  a0 |= (uint32_t)(lab[i] == c) << i;
    for (int i = 32; i < e1; i++) a1 |= (uint32_t)(lab[i] == c) << (i - 32);
    for (int i = 64; i < e2; i++) a2 |= (uint32_t)(lab[i] == c) << (i - 64);
    for (int i = 96; i < e3; i++) a3 |= (uint32_t)(lab[i] == c) << (i - 96);
    pq[0][c] = a0; pq[1][c] = a1; pq[2][c] = a2; pq[3][c] = a3;
  }
  __syncthreads();
  const bool active = (tid < NP);
  const int bpc = b * NP + (active ? tid : NP - 1);
  const int myel = elen[b];                 // uniform
  const int ntiles = (myel + TILE - 1) / TILE;

  DpState st;
  st.Pv0 = ~0ull; st.Pv1 = ~0ull; st.Mv0 = 0ull; st.Mv1 = 0ull;
  st.score = m; st.prev = -1; st.logp = 0.0;
  const int hw = (m - 1) >> 6;
  const u64 hmask = 1ull << ((m - 1) & 63);

  int2 bufA[TILE], bufB[TILE];
  load_tile(bufA, 0, tl, bpc);
  load_tile(bufB, 1, tl, bpc);
  for (int tile = 0; tile < ntiles; tile += 2) {
    process_tile(bufA, tile, myel, pq, hw, hmask, st);
    if (tile + 2 < ntiles) load_tile(bufA, tile + 2, tl, bpc);
    if (tile + 1 < ntiles) {
      process_tile(bufB, tile + 1, myel, pq, hw, hmask, st);
      if (tile + 3 < ntiles) load_tile(bufB, tile + 3, tl, bpc);
    }
  }
  if (active) { wer[bpc] = (float)st.score; logp_out[bpc] = (float)st.logp; }
}

// ---------------- Kernel 3: per-b softmax over P, expected WER, mean -----------
__global__ __launch_bounds__(512) void k_final(
    const float* __restrict__ wer, const float* __restrict__ logp,
    float* __restrict__ out) {
  __shared__ float partial[NB];
  const int w = threadIdx.x >> 6, lane = threadIdx.x & 63;
  const int base = w * NP;
  float l0 = (lane < NP) ? logp[base + lane] : -1e30f;
  float l1 = (lane + 64 < NP) ? logp[base + lane + 64] : -1e30f;
  float mx = fmaxf(l0, l1);
  for (int off = 1; off < 64; off <<= 1) mx = fmaxf(mx, __shfl_xor(mx, off));
  const float e0 = (lane < NP) ? __expf(l0 - mx) : 0.0f;
  const float e1 = (lane + 64 < NP) ? __expf(l1 - mx) : 0.0f;
  const float w0 = (lane < NP) ? wer[base + lane] : 0.0f;
  const float w1 = (lane + 64 < NP) ? wer[base + lane + 64] : 0.0f;
  float s = e0 + e1;
  float a = e0 * w0 + e1 * w1;
  for (int off = 1; off < 64; off <<= 1) {
    s += __shfl_xor(s, off);
    a += __shfl_xor(a, off);
  }
  if (lane == 0) partial[w] = a / s;
  __syncthreads();
  if (threadIdx.x == 0) {
    float tot = 0.0f;
    for (int i = 0; i < NB; i++) tot += partial[i];
    out[0] = tot * (1.0f / (float)NBP);
  }
}

extern "C" void kernel_launch(void* const* d_in, const int* in_sizes, int n_in,
                              void* d_out, int out_size, void* d_ws, size_t ws_size,
                              hipStream_t stream) {
  const float* em     = (const float*)d_in[0];
  const int*   elen   = (const int*)d_in[1];
  const int*   labels = (const int*)d_in[2];
  const int*   llen   = (const int*)d_in[3];
  float* out = (float*)d_out;
  char* ws = (char*)d_ws;
  int2*  tlb  = (int2*)ws;                                  // 500*800*8 = 3.2 MB
  float* wer  = (float*)(ws + (size_t)NT * NBP * 8);        // 3.2 KB
  float* logp = (float*)(ws + (size_t)NT * NBP * 8 + NBP * 4);

  k_sample<<<dim3(NB, NT), dim3(128), 0, stream>>>(em, elen, tlb);
  k_dp<<<dim3(NB), dim3(128), 0, stream>>>(tlb, elen, labels, llen, wer, logp);
  k_final<<<dim3(1), dim3(512), 0, stream>>>(wer, logp, out);
}

// Round 6
// 226.738 us; speedup vs baseline: 1.3441x; 1.0455x over previous
//
#include <hip/hip_runtime.h>
#include <stdint.h>

#define NB 8
#define NP 100
#define NT 500
#define NV 128
#define NBP 800   // NB*NP
#define TILE 8
#define TROWS 5   // t-rows per k_sample block (5*100 = 500 active of 512)

typedef unsigned long long u64;

// rotl via single v_alignbit_b32: alignbit(x,x,32-r) = rotr(x,32-r) = rotl(x,r)
#define ROTL(x, r) __builtin_amdgcn_alignbit((x), (x), 32 - (r))

// ---------------- Threefry-2x32, key = (0,1) (jax.random.key(1)) ----------------
__device__ __forceinline__ uint32_t threefry01_lo(uint32_t x0, uint32_t x1) {
  const uint32_t k0 = 0u, k1 = 1u;
  const uint32_t k2 = 0x1BD11BDAu ^ k0 ^ k1;  // 0x1BD11BDB
  x0 += k0; x1 += k1;
#define TF_R(r) { x0 += x1; x1 = ROTL(x1, r); x1 ^= x0; }
  TF_R(13) TF_R(15) TF_R(26) TF_R(6)
  x0 += k1; x1 += k2 + 1u;
  TF_R(17) TF_R(29) TF_R(16) TF_R(24)
  x0 += k2; x1 += k0 + 2u;
  TF_R(13) TF_R(15) TF_R(26) TF_R(6)
  x0 += k0; x1 += k1 + 3u;
  TF_R(17) TF_R(29) TF_R(16) TF_R(24)
  x0 += k1; x1 += k2 + 4u;
  TF_R(13) TF_R(15) TF_R(26) TF_R(6)
  x1 += k0 + 5u;            // o0 (x0 += k2) is dead — only the low word is used
#undef TF_R
  return x1;
}

// ---------------- Kernel 1: Gumbel sampling + serial argmin over V=128 ---------
// argmax_v(0.5*e + g_v)  ==  argmin_v((-log2 u_v) * exp(-0.5*e_v))
// row weights -exp2(e * -0.5*log2e) precomputed in LDS, shared by 100 paths.
// grid (NB, NT/TROWS), block 512: thread -> (r = tid/100, p = tid%100).
__global__ __launch_bounds__(512) void k_sample(
    const float* __restrict__ em, const int* __restrict__ elen,
    int2* __restrict__ tl) {
  const int b = blockIdx.x;
  const int t0 = blockIdx.y * TROWS;
  __shared__ float se[TROWS][NV];   // emissions rows
  __shared__ float snw[TROWS][NV];  // -exp2(e * -0.72134752)
  const int tid = threadIdx.x;
  const int el = elen[b];  // uniform
  for (int i = tid; i < TROWS * NV; i += 512) {
    const int r = i >> 7, v = i & 127;
    const float e = em[(size_t)((b * NT + t0 + r) << 7) + v];
    se[r][v] = e;
    snw[r][v] = -__builtin_amdgcn_exp2f(e * -0.7213475204444817f);  // 0.5*log2(e)
  }
  __syncthreads();
  if (tid >= TROWS * NP) return;
  const int r = tid / NP, p = tid - r * NP;
  const int t = t0 + r;
  if (t >= el) return;  // frames beyond length are never consumed
  const uint32_t base = (uint32_t)((b * NP + p) * NT + t) << 7;  // *NV
  const float span = (float)(1.0 - 1e-6) - 1e-6f;
  float best = 3.0e38f;
  int bi = 0;
#pragma unroll
  for (int v = 0; v < NV; v++) {
    // partitionable threefry: bits[i] = low output of threefry(key, i>>32, i)
    const uint32_t rnd = threefry01_lo(0u, base + (uint32_t)v);
    // exact bits->u chain (unchanged numerics vs passing rounds)
    const float f = __uint_as_float((rnd >> 9) | 0x3f800000u) - 1.0f;
    const float u = fmaxf(1e-6f, fmaf(f, span, 1e-6f));
    const float sc = __log2f(u) * snw[r][v];  // (-log2 u) * w  > 0
    if (sc < best) { best = sc; bi = v; }     // strict < = first-index tiebreak
  }
  tl[t * NBP + b * NP + p] = make_int2(bi, __float_as_int(se[r][bi]));
}

// ---------------- Kernel 2: CTC collapse + Myers bit-parallel edit distance ----
// one block per b (8 x 128), lane = path p (active p < 100). peq as 4 u32
// planes (bank = c%32, <=2-way). Global loads 2 tiles ahead; eq LDS reads 1
// tile ahead (extract/process split) so ds latency hides under Myers chain.
struct DpState {
  u64 Pv0, Pv1, Mv0, Mv1;
  int score, prev;
  double logp;
};

struct TileData {
  int cc[TILE];
  float ll[TILE];
  u64 eq0[TILE], eq1[TILE];
};

__device__ __forceinline__ void load_tile(int2 (&buf)[TILE], int tile,
                                          const int2* __restrict__ tl, int bpc) {
#pragma unroll
  for (int i = 0; i < TILE; i++) {
    int t = tile * TILE + i;
    t = t < NT ? t : NT - 1;
    buf[i] = tl[t * NBP + bpc];
  }
}

__device__ __forceinline__ void extract(const int2 (&buf)[TILE],
                                        const uint32_t (*pq)[NV], TileData& td) {
#pragma unroll
  for (int i = 0; i < TILE; i++) {
    td.cc[i] = buf[i].x;
    td.ll[i] = __int_as_float(buf[i].y);
    const int c = buf[i].x & 127;
    td.eq0[i] = (u64)pq[0][c] | ((u64)pq[1][c] << 32);
    td.eq1[i] = (u64)pq[2][c] | ((u64)pq[3][c] << 32);
  }
}

__device__ __forceinline__ void process_tile(const TileData& td, int tile,
                                             int myel, int hw, u64 hmask,
                                             DpState& st) {
#pragma unroll
  for (int i = 0; i < TILE; i++) {
    const int t = tile * TILE + i;
    if (t >= myel) break;  // uniform per block
    const int c = td.cc[i];
    const bool kept = (c != 0) && (c != st.prev);
    st.logp += (double)td.ll[i];
    st.prev = c;
    if (kept) {
      const u64 Eq0 = td.eq0[i], Eq1 = td.eq1[i];
      const u64 Xv0 = Eq0 | st.Mv0, Xv1 = Eq1 | st.Mv1;
      const u64 EP0 = Eq0 & st.Pv0, EP1 = Eq1 & st.Pv1;
      const u64 sA = EP0 + st.Pv0;
      const u64 sB = EP1 + st.Pv1 + (sA < EP0 ? 1ull : 0ull);
      const u64 Xh0 = (sA ^ st.Pv0) | Eq0;
      const u64 Xh1 = (sB ^ st.Pv1) | Eq1;
      const u64 Ph0 = st.Mv0 | ~(Xh0 | st.Pv0);
      const u64 Ph1 = st.Mv1 | ~(Xh1 | st.Pv1);
      const u64 Mh0 = st.Pv0 & Xh0, Mh1 = st.Pv1 & Xh1;
      st.score += (int)(((hw ? Ph1 : Ph0) & hmask) != 0);
      st.score -= (int)(((hw ? Mh1 : Mh0) & hmask) != 0);
      const u64 nPh1 = (Ph1 << 1) | (Ph0 >> 63);
      const u64 nPh0 = (Ph0 << 1) | 1ull;  // dp[i][0] = i boundary
      const u64 nMh1 = (Mh1 << 1) | (Mh0 >> 63);
      const u64 nMh0 = (Mh0 << 1);
      st.Pv0 = nMh0 | ~(Xv0 | nPh0);
      st.Pv1 = nMh1 | ~(Xv1 | nPh1);
      st.Mv0 = nPh0 & Xv0;
      st.Mv1 = nPh1 & Xv1;
    }
  }
}

__global__ __launch_bounds__(128) void k_dp(
    const int2* __restrict__ tl,
    const int* __restrict__ elen, const int* __restrict__ labels,
    const int* __restrict__ llen,
    float* __restrict__ wer, float* __restrict__ logp_out) {
  __shared__ uint32_t pq[4][NV];  // [word-half][token], 2 KB, bank = c%32
  const int b = blockIdx.x;
  const int tid = threadIdx.x;
  const int m = llen[b];  // ref_len in [80,100], uniform
  {
    const int c = tid;
    const int* __restrict__ lab = labels + b * 100;  // L == 100
    uint32_t a0 = 0, a1 = 0, a2 = 0, a3 = 0;
    const int e0 = m < 32 ? m : 32, e1 = m < 64 ? m : 64;
    const int e2 = m < 96 ? m : 96, e3 = m;
    for (int i = 0; i < e0; i++)  a0 |= (uint32_t)(lab[i] == c) << i;
    for (int i = 32; i < e1; i++) a1 |= (uint32_t)(lab[i] == c) << (i - 32);
    for (int i = 64; i < e2; i++) a2 |= (uint32_t)(lab[i] == c) << (i - 64);
    for (int i = 96; i < e3; i++) a3 |= (uint32_t)(lab[i] == c) << (i - 96);
    pq[0][c] = a0; pq[1][c] = a1; pq[2][c] = a2; pq[3][c] = a3;
  }
  __syncthreads();
  const bool active = (tid < NP);
  const int bpc = b * NP + (active ? tid : NP - 1);
  const int myel = elen[b];  // uniform
  const int ntiles = (myel + TILE - 1) / TILE;  // >= 50 always

  DpState st;
  st.Pv0 = ~0ull; st.Pv1 = ~0ull; st.Mv0 = 0ull; st.Mv1 = 0ull;
  st.score = m; st.prev = -1; st.logp = 0.0;
  const int hw = (m - 1) >> 6;
  const u64 hmask = 1ull << ((m - 1) & 63);

  int2 bufA[TILE], bufB[TILE];
  TileData TA, TB;
  load_tile(bufA, 0, tl, bpc);
  load_tile(bufB, 1, tl, bpc);
  extract(bufA, pq, TA);
  for (int tile = 0; tile < ntiles; tile += 2) {
    if (tile + 2 < ntiles) load_tile(bufA, tile + 2, tl, bpc);
    extract(bufB, pq, TB);                 // eq reads for tile+1 in flight
    process_tile(TA, tile, myel, hw, hmask, st);
    if (tile + 3 < ntiles) load_tile(bufB, tile + 3, tl, bpc);
    if (tile + 2 < ntiles) extract(bufA, pq, TA);  // tile+2 (global landed)
    if (tile + 1 < ntiles) process_tile(TB, tile + 1, myel, hw, hmask, st);
  }
  if (active) { wer[bpc] = (float)st.score; logp_out[bpc] = (float)st.logp; }
}

// ---------------- Kernel 3: per-b softmax over P, expected WER, mean -----------
__global__ __launch_bounds__(512) void k_final(
    const float* __restrict__ wer, const float* __restrict__ logp,
    float* __restrict__ out) {
  __shared__ float partial[NB];
  const int w = threadIdx.x >> 6, lane = threadIdx.x & 63;
  const int base = w * NP;
  float l0 = (lane < NP) ? logp[base + lane] : -1e30f;
  float l1 = (lane + 64 < NP) ? logp[base + lane + 64] : -1e30f;
  float mx = fmaxf(l0, l1);
  for (int off = 1; off < 64; off <<= 1) mx = fmaxf(mx, __shfl_xor(mx, off));
  const float e0 = (lane < NP) ? __expf(l0 - mx) : 0.0f;
  const float e1 = (lane + 64 < NP) ? __expf(l1 - mx) : 0.0f;
  const float w0 = (lane < NP) ? wer[base + lane] : 0.0f;
  const float w1 = (lane + 64 < NP) ? wer[base + lane + 64] : 0.0f;
  float s = e0 + e1;
  float a = e0 * w0 + e1 * w1;
  for (int off = 1; off < 64; off <<= 1) {
    s += __shfl_xor(s, off);
    a += __shfl_xor(a, off);
  }
  if (lane == 0) partial[w] = a / s;
  __syncthreads();
  if (threadIdx.x == 0) {
    float tot = 0.0f;
    for (int i = 0; i < NB; i++) tot += partial[i];
    out[0] = tot * (1.0f / (float)NBP);
  }
}

extern "C" void kernel_launch(void* const* d_in, const int* in_sizes, int n_in,
                              void* d_out, int out_size, void* d_ws, size_t ws_size,
                              hipStream_t stream) {
  const float* em     = (const float*)d_in[0];
  const int*   elen   = (const int*)d_in[1];
  const int*   labels = (const int*)d_in[2];
  const int*   llen   = (const int*)d_in[3];
  float* out = (float*)d_out;
  char* ws = (char*)d_ws;
  int2*  tlb  = (int2*)ws;                                  // 500*800*8 = 3.2 MB
  float* wer  = (float*)(ws + (size_t)NT * NBP * 8);        // 3.2 KB
  float* logp = (float*)(ws + (size_t)NT * NBP * 8 + NBP * 4);

  k_sample<<<dim3(NB, NT / TROWS), dim3(512), 0, stream>>>(em, elen, tlb);
  k_dp<<<dim3(NB), dim3(128), 0, stream>>>(tlb, elen, labels, llen, wer, logp);
  k_final<<<dim3(1), dim3(512), 0, stream>>>(wer, logp, out);
}